// Round 8
// baseline (215.396 us; speedup 1.0000x reference)
//
#include <hip/hip_runtime.h>
#include <hip/hip_bf16.h>
#include <math.h>

#define HID 128
#define BSEQ 8192
#define BSH 4096
#define RELS 1000
#define KEXT 256   // 128 elems x (hi,lo) bf16 interleaved
#define NTILE 64   // 64x64 output tiles
#define NTRI 2080  // 65*64/2 triangle tiles

typedef unsigned int u32;
typedef unsigned short u16;
typedef __attribute__((ext_vector_type(8))) short bf16x8;
typedef __attribute__((ext_vector_type(4))) float f32x4;

// d_ws layout (bytes)  [proven available: 4.25 MB]:
//  [64, 64+4000)         int winner[1000]
//  [4096, 53248)         float abc[3*4096]: a | b | c
//  [53248, 4247552)      float e[8192][128]
// d_out scratch (consumed by k_reduce BEFORE k_wrout overwrites):
//  byte 16:       ushort S[3][4096][256]   (u | ep | en, [hi,lo] pairs)  6.29 MB
//  byte 6291488:  double part_prep[4096][4]  (h2, r2, t2, wrsq)          128 KB
//  byte 6422560:  double part_margin[2080]                               16.6 KB

__device__ inline u16 f2bf(float x) {  // RNE bf16
    u32 u = __float_as_uint(x);
    u32 r = (u + 0x7fff + ((u >> 16) & 1)) >> 16;
    return (u16)r;
}

__device__ inline u32 pack2bf(float x) {  // [hi, lo] packed u32
    u16 hi = f2bf(x);
    float hf = __uint_as_float((u32)hi << 16);
    u16 lo = f2bf(x - hf);
    return (u32)hi | ((u32)lo << 16);
}

#define GLOAD_LDS16(g, l) __builtin_amdgcn_global_load_lds( \
    (const __attribute__((address_space(1))) u32*)(g), \
    (__attribute__((address_space(3))) u32*)(l), 16, 0, 0)

// inline-asm ds_read_b128: opaque to the waitcnt legalizer so the compiler
// cannot insert vmcnt(0) drains against outstanding global_load_lds (the
// R6/R7 pipeline killer). OFF must be a literal.
#define DSR(dst, addrv, OFF) \
    asm volatile("ds_read_b128 %0, %1 offset:" #OFF \
                 : "=v"(dst) : "v"(addrv))

__global__ void k_init(int* __restrict__ winner) {
    int t = blockIdx.x * blockDim.x + threadIdx.x;
    if (t < RELS) winner[t] = -1;
}

// Fused gather + norms + bf16-split + rowstats. Block b owns rows b (ep) and
// b+BSH (en). NO contended atomics: partials -> part_prep[b].
__global__ __launch_bounds__(256) void k_prep(const int* __restrict__ idx,
                                              const float* __restrict__ ent,
                                              const float* __restrict__ rel,
                                              float* __restrict__ e,
                                              u32* __restrict__ S,
                                              float* __restrict__ abc,
                                              int* __restrict__ winner,
                                              double* __restrict__ part) {
    const int b = blockIdx.x;
    const int half = threadIdx.x >> 7;   // 0=ep row b, 1=en row b+BSH
    const int k = threadIdx.x & 127;
    const int row = half ? (b + BSH) : b;
    const int i0 = idx[row * 3 + 0];
    const int i1 = idx[row * 3 + 1];
    const int i2 = idx[row * 3 + 2];
    const float h = ent[(size_t)i0 * HID + k];
    const float r = rel[(size_t)i1 * HID + k];
    const float t = ent[(size_t)i2 * HID + k];
    const float val = fabsf(h + r - t);
    e[(size_t)row * HID + k] = val;

    __shared__ float sE[2][128];
    __shared__ float sh[3][4];
    __shared__ float sPart[3][2];
    sE[half][k] = val;

    // norm partial sums (per wave)
    float hh = h * h, rr = r * r, tt = t * t;
    #pragma unroll
    for (int off = 32; off; off >>= 1) {
        hh += __shfl_down(hh, off);
        rr += __shfl_down(rr, off);
        tt += __shfl_down(tt, off);
    }
    int lane = threadIdx.x & 63, wv = threadIdx.x >> 6;
    if (lane == 0) { sh[0][wv] = hh; sh[1][wv] = rr; sh[2][wv] = tt; }
    __syncthreads();

    const float p = sE[0][k], n = sE[1][k];
    // bf16 splits: S row = 128 packed u32 ([hi,lo] per element; K-permutation ok)
    {
        size_t base = ((size_t)(1 + half) * BSH + b) * (KEXT / 2);
        S[base + k] = pack2bf(val);
        if (half == 0) {
            size_t ub = (size_t)b * (KEXT / 2);
            S[ub + k] = pack2bf(p + n);
        }
    }
    // rowstats on threads 0..127 (waves 0,1)
    if (half == 0) {
        float ak = p * n, bk = p * p, ck = n * n;
        #pragma unroll
        for (int off = 32; off; off >>= 1) {
            ak += __shfl_down(ak, off);
            bk += __shfl_down(bk, off);
            ck += __shfl_down(ck, off);
        }
        if (lane == 0) { sPart[0][wv] = ak; sPart[1][wv] = bk; sPart[2][wv] = ck; }
    }
    __syncthreads();
    if (threadIdx.x == 0) {
        float a = sPart[0][0] + sPart[0][1];
        float bb = sPart[1][0] + sPart[1][1];
        float c = sPart[2][0] + sPart[2][1];
        abc[b] = a; abc[BSH + b] = bb; abc[2 * BSH + b] = c;
        double ad = a, bd = bb, cd = c;
        part[(size_t)b * 4 + 0] = (double)(sh[0][0] + sh[0][1] + sh[0][2] + sh[0][3]);
        part[(size_t)b * 4 + 1] = (double)(sh[1][0] + sh[1][1] + sh[1][2] + sh[1][3]);
        part[(size_t)b * 4 + 2] = (double)(sh[2][0] + sh[2][1] + sh[2][2] + sh[2][3]);
        part[(size_t)b * 4 + 3] = cd * cd - 2.0 * ad * ad + bd * bd;
        atomicMax(&winner[i1], b);  // ~4 ops per address: uncontended
    }
}

// stage one BK=32 K-chunk of all 6 panels into LDS buffer (6 gload_lds / wave).
// LDS dest is linear (gload_lds constraint); SOURCE block is XOR-swizzled:
// LDS(row, bl) holds global block bl ^ ((row>>1)&3)  [T2 bank-conflict fix].
__device__ __forceinline__ void stage_chunk(const u16* __restrict__ S,
                                            int I0, int J0, int wv, int lane,
                                            int kc, u16* lds) {
    #pragma unroll
    for (int qq = 0; qq < 6; ++qq) {
        int q = wv * 6 + qq;
        int b = q * 1024 + lane * 16;      // byte cursor over 24KB
        int arr = b >> 12;                 // 0..5  (m*2+side)
        int within = b & 4095;
        int row = within >> 6;
        int colB = within & 63;
        int m = arr >> 1;
        int R0 = (arr & 1) ? J0 : I0;
        int sbl = (colB >> 4) ^ ((row >> 1) & 3);   // swizzled 16B-block idx
        const u16* src = S + ((size_t)(m * BSH + R0 + row) << 8)
                           + kc * 32 + (sbl << 3);
        GLOAD_LDS16(src, &lds[q * 512]);
    }
}

// MFMA Gram kernel, v4: 3-buffer rotation, ONE barrier per K-step, counted
// vmcnt(6), inline-asm ds_read_b128 (legalizer-opaque -> no forced drains).
// Hazard proof: step k reads buf[k%3]; stage(k+2) writes buf[(k+2)%3] (!=k%3).
// stage(k+2) vs step-(k-1) readers of the same buffer: every wave's MFMA(k-1)
// sits after an explicit lgkmcnt(0), so passing barrier(k) implies its reads
// completed; stage(k+2) is issued after barrier(k). vmcnt(6)+barrier implies
// all waves' stage(k) loads landed before any wave reads them.
// Three K=256 bf16 NT-GEMMs (q=u.u, p2=ep.ep, p3=en.en).
// score(i,j) = a_j*q + 1 - (a_j+b_j)*p2 - (a_j+c_j)*p3
__global__ __launch_bounds__(256) void k_scoremm(const u16* __restrict__ S,
                                                 const float* __restrict__ abc,
                                                 double* __restrict__ pm) {
    // XCD-chunked swizzle: 2080 = 8 x 260, bijective
    const int bid = blockIdx.x;
    const int f = (bid & 7) * (NTRI / 8) + (bid >> 3);
    // flat -> (bi, bj) with bi <= bj; off(bi) = bi*64 - bi*(bi-1)/2
    int bi = (int)(64.5f - sqrtf(64.5f * 64.5f - 2.0f * (float)f));
    while ((bi + 1) * NTILE - ((bi + 1) * bi) / 2 <= f) ++bi;
    while (bi * NTILE - (bi * (bi - 1)) / 2 > f) --bi;
    const int bj = bi + (f - (bi * NTILE - (bi * (bi - 1)) / 2));
    const int I0 = bi * 64, J0 = bj * 64;

    __shared__ __align__(16) u16 sAll[3][6 * 64 * 32];  // 3 x 24KB
    __shared__ float sRed[4];
    const int t = threadIdx.x;
    const int lane = t & 63, wv = t >> 6;
    const int wr = wv >> 1, wc = wv & 1;       // wave quadrant of 64x64
    const int lam = lane & 15, lag = lane >> 4;
    const int swz = (lam >> 1) & 3;            // matches stage-side XOR
    const unsigned fof = (unsigned)((lag ^ swz) << 4);   // frag byte offset

    const unsigned lbase =
        (unsigned)(unsigned long long)(__attribute__((address_space(3))) u16*)
            (u16*)&sAll[0][0];
    const unsigned aA0 = lbase + wr * 2048 + lam * 64 + fof;
    const unsigned aB0 = lbase + 4096 + wc * 2048 + lam * 64 + fof;

    f32x4 a0[2][2] = {}, a1[2][2] = {}, a2[2][2] = {};  // q, p2, p3 accums
    bf16x8 fa[3][2], fb[3][2];

    // prologue: 2 chunks in flight (12 loads/wave)
    stage_chunk(S, I0, J0, wv, lane, 0, &sAll[0][0]);
    stage_chunk(S, I0, J0, wv, lane, 1, &sAll[1][0]);

#define KSTEP(KC, NWAIT)                                                      \
    {                                                                         \
        asm volatile("s_waitcnt vmcnt(" #NWAIT ")" ::: "memory");             \
        __builtin_amdgcn_sched_barrier(0);                                    \
        __builtin_amdgcn_s_barrier();                                         \
        __builtin_amdgcn_sched_barrier(0);                                    \
        if ((KC) + 2 < 8)                                                     \
            stage_chunk(S, I0, J0, wv, lane, (KC) + 2,                        \
                        &sAll[((KC) + 2) % 3][0]);                            \
        const unsigned aA = aA0 + ((KC) % 3) * 24576u;                        \
        const unsigned aB = aB0 + ((KC) % 3) * 24576u;                        \
        DSR(fa[0][0], aA, 0);     DSR(fa[0][1], aA, 1024);                    \
        DSR(fa[1][0], aA, 8192);  DSR(fa[1][1], aA, 9216);                    \
        DSR(fa[2][0], aA, 16384); DSR(fa[2][1], aA, 17408);                   \
        DSR(fb[0][0], aB, 0);     DSR(fb[0][1], aB, 1024);                    \
        DSR(fb[1][0], aB, 8192);  DSR(fb[1][1], aB, 9216);                    \
        DSR(fb[2][0], aB, 16384); DSR(fb[2][1], aB, 17408);                   \
        asm volatile("s_waitcnt lgkmcnt(0)" ::: "memory");                    \
        __builtin_amdgcn_sched_barrier(0);                                    \
        _Pragma("unroll")                                                     \
        for (int fi = 0; fi < 2; ++fi) {                                      \
            _Pragma("unroll")                                                 \
            for (int fj = 0; fj < 2; ++fj) {                                  \
                a0[fi][fj] = __builtin_amdgcn_mfma_f32_16x16x32_bf16(         \
                    fa[0][fi], fb[0][fj], a0[fi][fj], 0, 0, 0);               \
                a1[fi][fj] = __builtin_amdgcn_mfma_f32_16x16x32_bf16(         \
                    fa[1][fi], fb[1][fj], a1[fi][fj], 0, 0, 0);               \
                a2[fi][fj] = __builtin_amdgcn_mfma_f32_16x16x32_bf16(         \
                    fa[2][fi], fb[2][fj], a2[fi][fj], 0, 0, 0);               \
            }                                                                 \
        }                                                                     \
    }

    KSTEP(0, 6) KSTEP(1, 6) KSTEP(2, 6) KSTEP(3, 6)
    KSTEP(4, 6) KSTEP(5, 6) KSTEP(6, 6) KSTEP(7, 0)
#undef KSTEP

    // epilogue: C layout col=lane&15, row=(lane>>4)*4+reg (m89-verified)
    const float* A = abc;
    const float* Bv = abc + BSH;
    const float* Cv = abc + 2 * BSH;
    float lsum = 0.f;
    #pragma unroll
    for (int fj = 0; fj < 2; ++fj) {
        int j = J0 + wc * 32 + fj * 16 + lam;
        float aj = A[j], abj = aj + Bv[j], acj = aj + Cv[j];
        #pragma unroll
        for (int fi = 0; fi < 2; ++fi)
            #pragma unroll
            for (int r = 0; r < 4; ++r) {
                float s = fmaf(aj, a0[fi][fj][r], 1.0f)
                          - abj * a1[fi][fj][r] - acj * a2[fi][fj][r];
                lsum += fmaxf(s, 0.f);
            }
    }
    if (bj != bi) {
        #pragma unroll
        for (int fi = 0; fi < 2; ++fi)
            #pragma unroll
            for (int r = 0; r < 4; ++r) {
                int i = I0 + wr * 32 + fi * 16 + lag * 4 + r;
                float ai = A[i], abi = ai + Bv[i], aci = ai + Cv[i];
                #pragma unroll
                for (int fj = 0; fj < 2; ++fj) {
                    float s = fmaf(ai, a0[fi][fj][r], 1.0f)
                              - abi * a1[fi][fj][r] - aci * a2[fi][fj][r];
                    lsum += fmaxf(s, 0.f);
                }
            }
    }
    #pragma unroll
    for (int off = 32; off; off >>= 1) lsum += __shfl_down(lsum, off);
    if (lane == 0) sRed[wv] = lsum;
    __syncthreads();
    if (t == 0)
        pm[f] = (double)(sRed[0] + sRed[1] + sRed[2] + sRed[3]);
}

// single-block tree reduce of all partials -> final loss scalar
__global__ __launch_bounds__(256) void k_reduce(const double* __restrict__ pp,
                                                const double* __restrict__ pm,
                                                float* __restrict__ out) {
    int t = threadIdx.x;
    double h2 = 0, r2 = 0, t2 = 0, wr = 0, mg = 0;
    for (int i = t; i < BSH; i += 256) {
        h2 += pp[(size_t)i * 4 + 0];
        r2 += pp[(size_t)i * 4 + 1];
        t2 += pp[(size_t)i * 4 + 2];
        wr += pp[(size_t)i * 4 + 3];
        if (i < NTRI) mg += pm[i];
    }
    #pragma unroll
    for (int off = 32; off; off >>= 1) {
        h2 += __shfl_down(h2, off);
        r2 += __shfl_down(r2, off);
        t2 += __shfl_down(t2, off);
        wr += __shfl_down(wr, off);
        mg += __shfl_down(mg, off);
    }
    __shared__ double sred[5][4];
    int lane = t & 63, wv = t >> 6;
    if (lane == 0) {
        sred[0][wv] = h2; sred[1][wv] = r2; sred[2][wv] = t2;
        sred[3][wv] = wr; sred[4][wv] = mg;
    }
    __syncthreads();
    if (t == 0) {
        double H = sred[0][0] + sred[0][1] + sred[0][2] + sred[0][3];
        double R = sred[1][0] + sred[1][1] + sred[1][2] + sred[1][3];
        double T = sred[2][0] + sred[2][1] + sred[2][2] + sred[2][3];
        double W = sred[3][0] + sred[3][1] + sred[3][2] + sred[3][3];
        double M = sred[4][0] + sred[4][1] + sred[4][2] + sred[4][3];
        out[0] = (float)(M / (double)BSH + sqrt(W) * 0.01
                         + (sqrt(H) + sqrt(R) + sqrt(T)) * 0.01);
    }
}

// one block per relation: write Wr_new row (runs LAST: d_out scratch dead)
__global__ __launch_bounds__(256) void k_wrout(const float* __restrict__ Wr,
                                               const float* __restrict__ e,
                                               const int* __restrict__ winner,
                                               float* __restrict__ outWr) {
    int rel = blockIdx.x;
    int t = threadIdx.x;
    float* out = outWr + (size_t)rel * HID * HID;
    int j = winner[rel];
    if (j < 0) {
        const float* src = Wr + (size_t)rel * HID * HID;
        #pragma unroll 8
        for (int it = 0; it < 64; ++it) out[it * 256 + t] = src[it * 256 + t];
    } else {
        __shared__ float sep[HID], sen[HID];
        if (t < 128) sep[t] = e[(size_t)j * HID + t];
        else sen[t - 128] = e[(size_t)(j + BSH) * HID + (t - 128)];
        __syncthreads();
        #pragma unroll 8
        for (int it = 0; it < 64; ++it) {
            int ix = it * 256 + t;
            int hh = ix >> 7, kk = ix & 127;
            out[ix] = sen[hh] * sen[kk] - sep[hh] * sep[kk];
        }
    }
}

extern "C" void kernel_launch(void* const* d_in, const int* in_sizes, int n_in,
                              void* d_out, int out_size, void* d_ws, size_t ws_size,
                              hipStream_t stream) {
    const int* idx = (const int*)d_in[0];
    const float* ent = (const float*)d_in[1];
    const float* rel = (const float*)d_in[2];
    const float* Wr = (const float*)d_in[3];
    float* out = (float*)d_out;

    char* ws = (char*)d_ws;
    int* winner = (int*)(ws + 64);
    float* abc = (float*)(ws + 4096);
    float* e = (float*)(ws + 53248);
    // scratch in d_out (65.5 MB); consumed before k_wrout overwrites
    u32* S = (u32*)(out + 4);
    double* pp = (double*)((char*)d_out + 6291488);
    double* pm = (double*)((char*)d_out + 6422560);

    k_init<<<4, 256, 0, stream>>>(winner);
    k_prep<<<BSH, 256, 0, stream>>>(idx, ent, rel, e, S, abc, winner, pp);
    k_scoremm<<<NTRI, 256, 0, stream>>>((const u16*)S, abc, pm);
    k_reduce<<<1, 256, 0, stream>>>(pp, pm, out);
    k_wrout<<<RELS, 256, 0, stream>>>(Wr, e, winner, out + 1);
}

// Round 10
// 207.349 us; speedup vs baseline: 1.0388x; 1.0388x over previous
//
#include <hip/hip_runtime.h>
#include <hip/hip_bf16.h>
#include <math.h>

#define HID 128
#define BSEQ 8192
#define BSH 4096
#define RELS 1000
#define NTILE 64   // 64x64 output tiles
#define NTRI 2080  // 65*64/2 triangle tiles
#define PSTRIDE 524288  // u32 per panel: 32 chunks * 4096 rows * 4

typedef unsigned int u32;
typedef unsigned short u16;
typedef __attribute__((ext_vector_type(8))) short bf16x8;
typedef __attribute__((ext_vector_type(4))) float f32x4;

// d_ws layout (bytes):
//  [64, 64+4000)         int winner[1000]
//  [4096, 53248)         float abc[3*4096]: a | b | c
//  [53248, 4247552)      float e[8192][128]
// d_out scratch (consumed BEFORE k_wrout overwrites):
//  byte 16:       u32 S[3][32][4096][4]  K-MAJOR bf16-pair panels   6.29 MB
//                 (panel m, pair-chunk c, row, pair-in-chunk; pair=[hi,lo])
//  byte 6291488:  double part_prep[4096][4]  (h2, r2, t2, wrsq)     128 KB
//  byte 6422560:  double part_margin[2080]                          16.6 KB

__device__ inline u16 f2bf(float x) {  // RNE bf16
    u32 u = __float_as_uint(x);
    u32 r = (u + 0x7fff + ((u >> 16) & 1)) >> 16;
    return (u16)r;
}

__device__ inline u32 pack2bf(float x) {  // [hi, lo] packed u32 (2 k-slots)
    u16 hi = f2bf(x);
    float hf = __uint_as_float((u32)hi << 16);
    u16 lo = f2bf(x - hf);
    return (u32)hi | ((u32)lo << 16);
}

__global__ void k_init(int* __restrict__ winner) {
    int t = blockIdx.x * blockDim.x + threadIdx.x;
    if (t < RELS) winner[t] = -1;
}

// Fused gather + norms + bf16-split(K-major) + rowstats. Block b owns rows
// b (ep) and b+BSH (en). Partials -> part_prep[b] (no contended atomics).
__global__ __launch_bounds__(256) void k_prep(const int* __restrict__ idx,
                                              const float* __restrict__ ent,
                                              const float* __restrict__ rel,
                                              float* __restrict__ e,
                                              u32* __restrict__ S,
                                              float* __restrict__ abc,
                                              int* __restrict__ winner,
                                              double* __restrict__ part) {
    const int b = blockIdx.x;
    const int half = threadIdx.x >> 7;   // 0=ep row b, 1=en row b+BSH
    const int k = threadIdx.x & 127;     // element == bf16 pair index
    const int row = half ? (b + BSH) : b;
    const int i0 = idx[row * 3 + 0];
    const int i1 = idx[row * 3 + 1];
    const int i2 = idx[row * 3 + 2];
    const float h = ent[(size_t)i0 * HID + k];
    const float r = rel[(size_t)i1 * HID + k];
    const float t = ent[(size_t)i2 * HID + k];
    const float val = fabsf(h + r - t);
    e[(size_t)row * HID + k] = val;

    __shared__ float sE[2][128];
    __shared__ float sh[3][4];
    __shared__ float sPart[3][2];
    sE[half][k] = val;

    // norm partial sums (per wave)
    float hh = h * h, rr = r * r, tt = t * t;
    #pragma unroll
    for (int off = 32; off; off >>= 1) {
        hh += __shfl_down(hh, off);
        rr += __shfl_down(rr, off);
        tt += __shfl_down(tt, off);
    }
    int lane = threadIdx.x & 63, wv = threadIdx.x >> 6;
    if (lane == 0) { sh[0][wv] = hh; sh[1][wv] = rr; sh[2][wv] = tt; }
    __syncthreads();

    const float p = sE[0][k], n = sE[1][k];
    // K-major pair write: S[m][k>>2][row][k&3]
    {
        size_t kidx = ((size_t)(k >> 2) * BSH + b) * 4 + (k & 3);
        S[(size_t)(1 + half) * PSTRIDE + kidx] = pack2bf(val);
        if (half == 0) S[kidx] = pack2bf(p + n);
    }
    // rowstats on threads 0..127 (waves 0,1)
    if (half == 0) {
        float ak = p * n, bk = p * p, ck = n * n;
        #pragma unroll
        for (int off = 32; off; off >>= 1) {
            ak += __shfl_down(ak, off);
            bk += __shfl_down(bk, off);
            ck += __shfl_down(ck, off);
        }
        if (lane == 0) { sPart[0][wv] = ak; sPart[1][wv] = bk; sPart[2][wv] = ck; }
    }
    __syncthreads();
    if (threadIdx.x == 0) {
        float a = sPart[0][0] + sPart[0][1];
        float bb = sPart[1][0] + sPart[1][1];
        float c = sPart[2][0] + sPart[2][1];
        abc[b] = a; abc[BSH + b] = bb; abc[2 * BSH + b] = c;
        double ad = a, bd = bb, cd = c;
        part[(size_t)b * 4 + 0] = (double)(sh[0][0] + sh[0][1] + sh[0][2] + sh[0][3]);
        part[(size_t)b * 4 + 1] = (double)(sh[1][0] + sh[1][1] + sh[1][2] + sh[1][3]);
        part[(size_t)b * 4 + 2] = (double)(sh[2][0] + sh[2][1] + sh[2][2] + sh[2][3]);
        part[(size_t)b * 4 + 3] = cd * cd - 2.0 * ad * ad + bd * bd;
        atomicMax(&winner[i1], b);  // last-write-wins (max j)
    }
}

// MFMA Gram kernel v5: ZERO LDS staging, register-direct fragments.
// K-major S makes each MFMA fragment a coalesced 16B/lane global load
// (lanes 0-15 = contiguous 256B). No barriers in the K-loop; full unroll
// lets the compiler pipeline loads. Wave-pair A/B reuse hits L1.
// Three K=256 bf16 NT-GEMMs (q=u.u, p2=ep.ep, p3=en.en).
// score(i,j) = a_j*q + 1 - (a_j+b_j)*p2 - (a_j+c_j)*p3
__global__ __launch_bounds__(256) void k_scoremm(const u32* __restrict__ S,
                                                 const float* __restrict__ abc,
                                                 double* __restrict__ pm) {
    // XCD-chunked swizzle: 2080 = 8 x 260, bijective
    const int bid = blockIdx.x;
    const int f = (bid & 7) * (NTRI / 8) + (bid >> 3);
    // flat -> (bi, bj) with bi <= bj
    int bi = (int)(64.5f - sqrtf(64.5f * 64.5f - 2.0f * (float)f));
    while ((bi + 1) * NTILE - ((bi + 1) * bi) / 2 <= f) ++bi;
    while (bi * NTILE - (bi * (bi - 1)) / 2 > f) --bi;
    const int bj = bi + (f - (bi * NTILE - (bi * (bi - 1)) / 2));
    const int I0 = bi * 64, J0 = bj * 64;

    __shared__ float sRed[4];
    const int t = threadIdx.x;
    const int lane = t & 63, wv = t >> 6;
    const int wr = wv >> 1, wc = wv & 1;       // wave quadrant of 64x64
    const int lam = lane & 15, lag = lane >> 4;

    // frag address (u32 units): S[m*PSTRIDE + ((kc*4+lag)*4096 + row)*4]
    const u32* baseA = S + ((size_t)lag * BSH + I0 + wr * 32 + lam) * 4;
    const u32* baseB = S + ((size_t)lag * BSH + J0 + wc * 32 + lam) * 4;

    f32x4 a0[2][2] = {}, a1[2][2] = {}, a2[2][2] = {};  // q, p2, p3 accums

    #pragma unroll
    for (int kc = 0; kc < 8; ++kc) {
        bf16x8 fa[3][2], fb[3][2];
        #pragma unroll
        for (int m = 0; m < 3; ++m) {
            #pragma unroll
            for (int ff = 0; ff < 2; ++ff) {
                fa[m][ff] = *(const bf16x8*)(baseA + (size_t)m * PSTRIDE
                                             + kc * 65536 + ff * 64);
                fb[m][ff] = *(const bf16x8*)(baseB + (size_t)m * PSTRIDE
                                             + kc * 65536 + ff * 64);
            }
        }
        #pragma unroll
        for (int fi = 0; fi < 2; ++fi)
            #pragma unroll
            for (int fj = 0; fj < 2; ++fj) {
                a0[fi][fj] = __builtin_amdgcn_mfma_f32_16x16x32_bf16(
                    fa[0][fi], fb[0][fj], a0[fi][fj], 0, 0, 0);
                a1[fi][fj] = __builtin_amdgcn_mfma_f32_16x16x32_bf16(
                    fa[1][fi], fb[1][fj], a1[fi][fj], 0, 0, 0);
                a2[fi][fj] = __builtin_amdgcn_mfma_f32_16x16x32_bf16(
                    fa[2][fi], fb[2][fj], a2[fi][fj], 0, 0, 0);
            }
    }

    // epilogue: C layout col=lane&15, row=(lane>>4)*4+reg (m89-verified)
    const float* A = abc;
    const float* Bv = abc + BSH;
    const float* Cv = abc + 2 * BSH;
    float lsum = 0.f;
    #pragma unroll
    for (int fj = 0; fj < 2; ++fj) {
        int j = J0 + wc * 32 + fj * 16 + lam;
        float aj = A[j], abj = aj + Bv[j], acj = aj + Cv[j];
        #pragma unroll
        for (int fi = 0; fi < 2; ++fi)
            #pragma unroll
            for (int r = 0; r < 4; ++r) {
                float s = fmaf(aj, a0[fi][fj][r], 1.0f)
                          - abj * a1[fi][fj][r] - acj * a2[fi][fj][r];
                lsum += fmaxf(s, 0.f);
            }
    }
    if (bj != bi) {
        #pragma unroll
        for (int fi = 0; fi < 2; ++fi)
            #pragma unroll
            for (int r = 0; r < 4; ++r) {
                int i = I0 + wr * 32 + fi * 16 + lag * 4 + r;
                float ai = A[i], abi = ai + Bv[i], aci = ai + Cv[i];
                #pragma unroll
                for (int fj = 0; fj < 2; ++fj) {
                    float s = fmaf(ai, a0[fi][fj][r], 1.0f)
                              - abi * a1[fi][fj][r] - aci * a2[fi][fj][r];
                    lsum += fmaxf(s, 0.f);
                }
            }
    }
    #pragma unroll
    for (int off = 32; off; off >>= 1) lsum += __shfl_down(lsum, off);
    if (lane == 0) sRed[wv] = lsum;
    __syncthreads();
    if (t == 0)
        pm[f] = (double)(sRed[0] + sRed[1] + sRed[2] + sRed[3]);
}

// single-block tree reduce of all partials -> final loss scalar
__global__ __launch_bounds__(256) void k_reduce(const double* __restrict__ pp,
                                                const double* __restrict__ pm,
                                                float* __restrict__ out) {
    int t = threadIdx.x;
    double h2 = 0, r2 = 0, t2 = 0, wr = 0, mg = 0;
    for (int i = t; i < BSH; i += 256) {
        h2 += pp[(size_t)i * 4 + 0];
        r2 += pp[(size_t)i * 4 + 1];
        t2 += pp[(size_t)i * 4 + 2];
        wr += pp[(size_t)i * 4 + 3];
        if (i < NTRI) mg += pm[i];
    }
    #pragma unroll
    for (int off = 32; off; off >>= 1) {
        h2 += __shfl_down(h2, off);
        r2 += __shfl_down(r2, off);
        t2 += __shfl_down(t2, off);
        wr += __shfl_down(wr, off);
        mg += __shfl_down(mg, off);
    }
    __shared__ double sred[5][4];
    int lane = t & 63, wv = t >> 6;
    if (lane == 0) {
        sred[0][wv] = h2; sred[1][wv] = r2; sred[2][wv] = t2;
        sred[3][wv] = wr; sred[4][wv] = mg;
    }
    __syncthreads();
    if (t == 0) {
        double H = sred[0][0] + sred[0][1] + sred[0][2] + sred[0][3];
        double R = sred[1][0] + sred[1][1] + sred[1][2] + sred[1][3];
        double T = sred[2][0] + sred[2][1] + sred[2][2] + sred[2][3];
        double W = sred[3][0] + sred[3][1] + sred[3][2] + sred[3][3];
        double M = sred[4][0] + sred[4][1] + sred[4][2] + sred[4][3];
        out[0] = (float)(M / (double)BSH + sqrt(W) * 0.01
                         + (sqrt(H) + sqrt(R) + sqrt(T)) * 0.01);
    }
}

// one block per relation: write Wr_new row (runs LAST: d_out scratch dead)
__global__ __launch_bounds__(256) void k_wrout(const float* __restrict__ Wr,
                                               const float* __restrict__ e,
                                               const int* __restrict__ winner,
                                               float* __restrict__ outWr) {
    int rel = blockIdx.x;
    int t = threadIdx.x;
    float* out = outWr + (size_t)rel * HID * HID;
    int j = winner[rel];
    if (j < 0) {
        const float* src = Wr + (size_t)rel * HID * HID;
        #pragma unroll 8
        for (int it = 0; it < 64; ++it) out[it * 256 + t] = src[it * 256 + t];
    } else {
        __shared__ float sep[HID], sen[HID];
        if (t < 128) sep[t] = e[(size_t)j * HID + t];
        else sen[t - 128] = e[(size_t)(j + BSH) * HID + (t - 128)];
        __syncthreads();
        #pragma unroll 8
        for (int it = 0; it < 64; ++it) {
            int ix = it * 256 + t;
            int hh = ix >> 7, kk = ix & 127;
            out[ix] = sen[hh] * sen[kk] - sep[hh] * sep[kk];
        }
    }
}

extern "C" void kernel_launch(void* const* d_in, const int* in_sizes, int n_in,
                              void* d_out, int out_size, void* d_ws, size_t ws_size,
                              hipStream_t stream) {
    const int* idx = (const int*)d_in[0];
    const float* ent = (const float*)d_in[1];
    const float* rel = (const float*)d_in[2];
    const float* Wr = (const float*)d_in[3];
    float* out = (float*)d_out;

    char* ws = (char*)d_ws;
    int* winner = (int*)(ws + 64);
    float* abc = (float*)(ws + 4096);
    float* e = (float*)(ws + 53248);
    // scratch in d_out (65.5 MB); consumed before k_wrout overwrites
    u32* S = (u32*)(out + 4);
    double* pp = (double*)((char*)d_out + 6291488);
    double* pm = (double*)((char*)d_out + 6422560);

    k_init<<<4, 256, 0, stream>>>(winner);
    k_prep<<<BSH, 256, 0, stream>>>(idx, ent, rel, e, S, abc, winner, pp);
    k_scoremm<<<NTRI, 256, 0, stream>>>(S, abc, pm);
    k_reduce<<<1, 256, 0, stream>>>(pp, pm, out);
    k_wrout<<<RELS, 256, 0, stream>>>(Wr, e, winner, out + 1);
}

// Round 11
// 203.710 us; speedup vs baseline: 1.0574x; 1.0179x over previous
//
#include <hip/hip_runtime.h>
#include <hip/hip_bf16.h>
#include <math.h>

#define HID 128
#define BSEQ 8192
#define BSH 4096
#define RELS 1000
#define NTILE 64   // 64x64 output tiles
#define NTRI 2080  // 65*64/2 triangle tiles
#define PSTRIDE 524288  // u32 per panel: 32 chunks * 4096 rows * 4

typedef unsigned int u32;
typedef unsigned short u16;
typedef __attribute__((ext_vector_type(8))) short bf16x8;
typedef __attribute__((ext_vector_type(4))) float f32x4;

// d_ws layout (bytes):
//  [64, 64+4000)         int winner[1000]
//  [4096, 53248)         float abc[3*4096]: a | b | c
//  [53248, 4247552)      float e[8192][128]
// d_out scratch (consumed BEFORE k_wrout overwrites):
//  byte 16:       u32 S[3][32][4096][4]  K-MAJOR bf16-pair panels   6.29 MB
//                 (panel m, pair-chunk c, row, pair-in-chunk; pair=[hi,lo])
//  byte 6291488:  double part_prep[4096][4]  (h2, r2, t2, wrsq)     128 KB
//  byte 6422560:  double part_margin[2080]                          16.6 KB

__device__ inline u16 f2bf(float x) {  // RNE bf16
    u32 u = __float_as_uint(x);
    u32 r = (u + 0x7fff + ((u >> 16) & 1)) >> 16;
    return (u16)r;
}

__device__ inline u32 pack2bf(float x) {  // [hi, lo] packed u32 (2 k-slots)
    u16 hi = f2bf(x);
    float hf = __uint_as_float((u32)hi << 16);
    u16 lo = f2bf(x - hf);
    return (u32)hi | ((u32)lo << 16);
}

__global__ void k_init(int* __restrict__ winner) {
    int t = blockIdx.x * blockDim.x + threadIdx.x;
    if (t < RELS) winner[t] = -1;
}

// Fused gather + norms + bf16-split(K-major) + rowstats. Block b owns rows
// b (ep) and b+BSH (en). Partials -> part_prep[b] (no contended atomics).
__global__ __launch_bounds__(256) void k_prep(const int* __restrict__ idx,
                                              const float* __restrict__ ent,
                                              const float* __restrict__ rel,
                                              float* __restrict__ e,
                                              u32* __restrict__ S,
                                              float* __restrict__ abc,
                                              int* __restrict__ winner,
                                              double* __restrict__ part) {
    const int b = blockIdx.x;
    const int half = threadIdx.x >> 7;   // 0=ep row b, 1=en row b+BSH
    const int k = threadIdx.x & 127;     // element == bf16 pair index
    const int row = half ? (b + BSH) : b;
    const int i0 = idx[row * 3 + 0];
    const int i1 = idx[row * 3 + 1];
    const int i2 = idx[row * 3 + 2];
    const float h = ent[(size_t)i0 * HID + k];
    const float r = rel[(size_t)i1 * HID + k];
    const float t = ent[(size_t)i2 * HID + k];
    const float val = fabsf(h + r - t);
    e[(size_t)row * HID + k] = val;

    __shared__ float sE[2][128];
    __shared__ float sh[3][4];
    __shared__ float sPart[3][2];
    sE[half][k] = val;

    // norm partial sums (per wave)
    float hh = h * h, rr = r * r, tt = t * t;
    #pragma unroll
    for (int off = 32; off; off >>= 1) {
        hh += __shfl_down(hh, off);
        rr += __shfl_down(rr, off);
        tt += __shfl_down(tt, off);
    }
    int lane = threadIdx.x & 63, wv = threadIdx.x >> 6;
    if (lane == 0) { sh[0][wv] = hh; sh[1][wv] = rr; sh[2][wv] = tt; }
    __syncthreads();

    const float p = sE[0][k], n = sE[1][k];
    // K-major pair write: S[m][k>>2][row][k&3]
    {
        size_t kidx = ((size_t)(k >> 2) * BSH + b) * 4 + (k & 3);
        S[(size_t)(1 + half) * PSTRIDE + kidx] = pack2bf(val);
        if (half == 0) S[kidx] = pack2bf(p + n);
    }
    // rowstats on threads 0..127 (waves 0,1)
    if (half == 0) {
        float ak = p * n, bk = p * p, ck = n * n;
        #pragma unroll
        for (int off = 32; off; off >>= 1) {
            ak += __shfl_down(ak, off);
            bk += __shfl_down(bk, off);
            ck += __shfl_down(ck, off);
        }
        if (lane == 0) { sPart[0][wv] = ak; sPart[1][wv] = bk; sPart[2][wv] = ck; }
    }
    __syncthreads();
    if (threadIdx.x == 0) {
        float a = sPart[0][0] + sPart[0][1];
        float bb = sPart[1][0] + sPart[1][1];
        float c = sPart[2][0] + sPart[2][1];
        abc[b] = a; abc[BSH + b] = bb; abc[2 * BSH + b] = c;
        double ad = a, bd = bb, cd = c;
        part[(size_t)b * 4 + 0] = (double)(sh[0][0] + sh[0][1] + sh[0][2] + sh[0][3]);
        part[(size_t)b * 4 + 1] = (double)(sh[1][0] + sh[1][1] + sh[1][2] + sh[1][3]);
        part[(size_t)b * 4 + 2] = (double)(sh[2][0] + sh[2][1] + sh[2][2] + sh[2][3]);
        part[(size_t)b * 4 + 3] = cd * cd - 2.0 * ad * ad + bd * bd;
        atomicMax(&winner[i1], b);  // last-write-wins (max j)
    }
}

// MFMA Gram kernel v6: register-direct + explicit 2-deep fragment double
// buffer + __launch_bounds__(256,2) so the allocator has ~256 VGPRs (v5's
// VGPR_Count=76 starved ILP and serialized loads). Static even/odd buffers
// (rule-#20: no runtime indexing). No LDS, no barriers in the K-loop.
// Three K=256 bf16 NT-GEMMs (q=u.u, p2=ep.ep, p3=en.en).
// score(i,j) = a_j*q + 1 - (a_j+b_j)*p2 - (a_j+c_j)*p3
__global__ __launch_bounds__(256, 2) void k_scoremm(const u32* __restrict__ S,
                                                    const float* __restrict__ abc,
                                                    double* __restrict__ pm) {
    // XCD-chunked swizzle: 2080 = 8 x 260, bijective
    const int bid = blockIdx.x;
    const int f = (bid & 7) * (NTRI / 8) + (bid >> 3);
    // flat -> (bi, bj) with bi <= bj
    int bi = (int)(64.5f - sqrtf(64.5f * 64.5f - 2.0f * (float)f));
    while ((bi + 1) * NTILE - ((bi + 1) * bi) / 2 <= f) ++bi;
    while (bi * NTILE - (bi * (bi - 1)) / 2 > f) --bi;
    const int bj = bi + (f - (bi * NTILE - (bi * (bi - 1)) / 2));
    const int I0 = bi * 64, J0 = bj * 64;

    __shared__ float sRed[4];
    const int t = threadIdx.x;
    const int lane = t & 63, wv = t >> 6;
    const int wr = wv >> 1, wc = wv & 1;       // wave quadrant of 64x64
    const int lam = lane & 15, lag = lane >> 4;

    // frag address (u32 units): S[m*PSTRIDE + ((kc*4+lag)*4096 + row)*4]
    const u32* baseA = S + ((size_t)lag * BSH + I0 + wr * 32 + lam) * 4;
    const u32* baseB = S + ((size_t)lag * BSH + J0 + wc * 32 + lam) * 4;

    f32x4 a0[2][2] = {}, a1[2][2] = {}, a2[2][2] = {};  // q, p2, p3 accums
    bf16x8 faE[3][2], fbE[3][2], faO[3][2], fbO[3][2];  // even/odd frag bufs

#define LOADF(FA, FB, KC)                                                     \
    _Pragma("unroll")                                                         \
    for (int m = 0; m < 3; ++m) {                                             \
        _Pragma("unroll")                                                     \
        for (int ff = 0; ff < 2; ++ff) {                                      \
            FA[m][ff] = *(const bf16x8*)(baseA + (size_t)m * PSTRIDE          \
                                         + (KC) * 65536 + ff * 64);           \
            FB[m][ff] = *(const bf16x8*)(baseB + (size_t)m * PSTRIDE          \
                                         + (KC) * 65536 + ff * 64);           \
        }                                                                     \
    }

#define MFMAS(FA, FB)                                                         \
    _Pragma("unroll")                                                         \
    for (int fi = 0; fi < 2; ++fi) {                                          \
        _Pragma("unroll")                                                     \
        for (int fj = 0; fj < 2; ++fj) {                                      \
            a0[fi][fj] = __builtin_amdgcn_mfma_f32_16x16x32_bf16(             \
                FA[0][fi], FB[0][fj], a0[fi][fj], 0, 0, 0);                   \
            a1[fi][fj] = __builtin_amdgcn_mfma_f32_16x16x32_bf16(             \
                FA[1][fi], FB[1][fj], a1[fi][fj], 0, 0, 0);                   \
            a2[fi][fj] = __builtin_amdgcn_mfma_f32_16x16x32_bf16(             \
                FA[2][fi], FB[2][fj], a2[fi][fj], 0, 0, 0);                   \
        }                                                                     \
    }

    LOADF(faE, fbE, 0)
    LOADF(faO, fbO, 1)   // 24 loads in flight before first MFMA
    MFMAS(faE, fbE)      // kc=0
    LOADF(faE, fbE, 2)
    MFMAS(faO, fbO)      // kc=1
    LOADF(faO, fbO, 3)
    MFMAS(faE, fbE)      // kc=2
    LOADF(faE, fbE, 4)
    MFMAS(faO, fbO)      // kc=3
    LOADF(faO, fbO, 5)
    MFMAS(faE, fbE)      // kc=4
    LOADF(faE, fbE, 6)
    MFMAS(faO, fbO)      // kc=5
    LOADF(faO, fbO, 7)
    MFMAS(faE, fbE)      // kc=6
    MFMAS(faO, fbO)      // kc=7
#undef LOADF
#undef MFMAS

    // epilogue: C layout col=lane&15, row=(lane>>4)*4+reg (m89-verified)
    const float* A = abc;
    const float* Bv = abc + BSH;
    const float* Cv = abc + 2 * BSH;
    float lsum = 0.f;
    #pragma unroll
    for (int fj = 0; fj < 2; ++fj) {
        int j = J0 + wc * 32 + fj * 16 + lam;
        float aj = A[j], abj = aj + Bv[j], acj = aj + Cv[j];
        #pragma unroll
        for (int fi = 0; fi < 2; ++fi)
            #pragma unroll
            for (int r = 0; r < 4; ++r) {
                float s = fmaf(aj, a0[fi][fj][r], 1.0f)
                          - abj * a1[fi][fj][r] - acj * a2[fi][fj][r];
                lsum += fmaxf(s, 0.f);
            }
    }
    if (bj != bi) {
        #pragma unroll
        for (int fi = 0; fi < 2; ++fi)
            #pragma unroll
            for (int r = 0; r < 4; ++r) {
                int i = I0 + wr * 32 + fi * 16 + lag * 4 + r;
                float ai = A[i], abi = ai + Bv[i], aci = ai + Cv[i];
                #pragma unroll
                for (int fj = 0; fj < 2; ++fj) {
                    float s = fmaf(ai, a0[fi][fj][r], 1.0f)
                              - abi * a1[fi][fj][r] - aci * a2[fi][fj][r];
                    lsum += fmaxf(s, 0.f);
                }
            }
    }
    #pragma unroll
    for (int off = 32; off; off >>= 1) lsum += __shfl_down(lsum, off);
    if (lane == 0) sRed[wv] = lsum;
    __syncthreads();
    if (t == 0)
        pm[f] = (double)(sRed[0] + sRed[1] + sRed[2] + sRed[3]);
}

// single-block tree reduce of all partials -> final loss scalar
__global__ __launch_bounds__(256) void k_reduce(const double* __restrict__ pp,
                                                const double* __restrict__ pm,
                                                float* __restrict__ out) {
    int t = threadIdx.x;
    double h2 = 0, r2 = 0, t2 = 0, wr = 0, mg = 0;
    for (int i = t; i < BSH; i += 256) {
        h2 += pp[(size_t)i * 4 + 0];
        r2 += pp[(size_t)i * 4 + 1];
        t2 += pp[(size_t)i * 4 + 2];
        wr += pp[(size_t)i * 4 + 3];
        if (i < NTRI) mg += pm[i];
    }
    #pragma unroll
    for (int off = 32; off; off >>= 1) {
        h2 += __shfl_down(h2, off);
        r2 += __shfl_down(r2, off);
        t2 += __shfl_down(t2, off);
        wr += __shfl_down(wr, off);
        mg += __shfl_down(mg, off);
    }
    __shared__ double sred[5][4];
    int lane = t & 63, wv = t >> 6;
    if (lane == 0) {
        sred[0][wv] = h2; sred[1][wv] = r2; sred[2][wv] = t2;
        sred[3][wv] = wr; sred[4][wv] = mg;
    }
    __syncthreads();
    if (t == 0) {
        double H = sred[0][0] + sred[0][1] + sred[0][2] + sred[0][3];
        double R = sred[1][0] + sred[1][1] + sred[1][2] + sred[1][3];
        double T = sred[2][0] + sred[2][1] + sred[2][2] + sred[2][3];
        double W = sred[3][0] + sred[3][1] + sred[3][2] + sred[3][3];
        double M = sred[4][0] + sred[4][1] + sred[4][2] + sred[4][3];
        out[0] = (float)(M / (double)BSH + sqrt(W) * 0.01
                         + (sqrt(H) + sqrt(R) + sqrt(T)) * 0.01);
    }
}

// one block per relation: write Wr_new row (runs LAST: d_out scratch dead)
__global__ __launch_bounds__(256) void k_wrout(const float* __restrict__ Wr,
                                               const float* __restrict__ e,
                                               const int* __restrict__ winner,
                                               float* __restrict__ outWr) {
    int rel = blockIdx.x;
    int t = threadIdx.x;
    float* out = outWr + (size_t)rel * HID * HID;
    int j = winner[rel];
    if (j < 0) {
        const float* src = Wr + (size_t)rel * HID * HID;
        #pragma unroll 8
        for (int it = 0; it < 64; ++it) out[it * 256 + t] = src[it * 256 + t];
    } else {
        __shared__ float sep[HID], sen[HID];
        if (t < 128) sep[t] = e[(size_t)j * HID + t];
        else sen[t - 128] = e[(size_t)(j + BSH) * HID + (t - 128)];
        __syncthreads();
        #pragma unroll 8
        for (int it = 0; it < 64; ++it) {
            int ix = it * 256 + t;
            int hh = ix >> 7, kk = ix & 127;
            out[ix] = sen[hh] * sen[kk] - sep[hh] * sep[kk];
        }
    }
}

extern "C" void kernel_launch(void* const* d_in, const int* in_sizes, int n_in,
                              void* d_out, int out_size, void* d_ws, size_t ws_size,
                              hipStream_t stream) {
    const int* idx = (const int*)d_in[0];
    const float* ent = (const float*)d_in[1];
    const float* rel = (const float*)d_in[2];
    const float* Wr = (const float*)d_in[3];
    float* out = (float*)d_out;

    char* ws = (char*)d_ws;
    int* winner = (int*)(ws + 64);
    float* abc = (float*)(ws + 4096);
    float* e = (float*)(ws + 53248);
    // scratch in d_out (65.5 MB); consumed before k_wrout overwrites
    u32* S = (u32*)(out + 4);
    double* pp = (double*)((char*)d_out + 6291488);
    double* pm = (double*)((char*)d_out + 6422560);

    k_init<<<4, 256, 0, stream>>>(winner);
    k_prep<<<BSH, 256, 0, stream>>>(idx, ent, rel, e, S, abc, winner, pp);
    k_scoremm<<<NTRI, 256, 0, stream>>>(S, abc, pm);
    k_reduce<<<1, 256, 0, stream>>>(pp, pm, out);
    k_wrout<<<RELS, 256, 0, stream>>>(Wr, e, winner, out + 1);
}